// Round 5
// baseline (1012.151 us; speedup 1.0000x reference)
//
#include <hip/hip_runtime.h>
#include <hip/hip_bf16.h>
#include <math.h>

// Problem dims
#define BQ 8
#define SQ 512
#define HID 768
#define NH 12
#define DH 64
#define INTER 3072
#define NL 4
#define M_TOK (BQ*SQ)   // 4096 tokens

typedef unsigned short ushort_t;
typedef __attribute__((ext_vector_type(8))) short bf16x8;
typedef __attribute__((ext_vector_type(8))) unsigned short u16x8;
typedef __attribute__((ext_vector_type(4))) float f32x4;

__device__ __forceinline__ float bf2f(ushort_t u) {
  union { float f; unsigned int i; } v; v.i = ((unsigned int)u) << 16; return v.f;
}
__device__ __forceinline__ ushort_t f2bf(float f) {
  __hip_bfloat16 h = __float2bfloat16(f);
  return *reinterpret_cast<ushort_t*>(&h);
}

__device__ __forceinline__ void gload_lds16(const ushort_t* g, ushort_t* l) {
  __builtin_amdgcn_global_load_lds(
      (const __attribute__((address_space(1))) void*)g,
      (__attribute__((address_space(3))) void*)l, 16, 0, 0);
}

// ---------------------------------------------------------------------------
// prep: maskf, maskbias, h = hidden*mask (fp32) + hb (bf16)
// ---------------------------------------------------------------------------
__global__ __launch_bounds__(256) void prep_kernel(
    const float* __restrict__ hidden, const float* __restrict__ amask,
    float* __restrict__ maskf, float* __restrict__ maskbias,
    float* __restrict__ h, ushort_t* __restrict__ hb)
{
  int i = blockIdx.x * 256 + threadIdx.x;
  if (i < M_TOK * HID) {
    float m = amask[i / HID];
    float v = hidden[i] * m;
    h[i] = v;
    hb[i] = f2bf(v);
    if (i < M_TOK) {
      maskf[i] = amask[i];
      maskbias[i] = (1.0f - amask[i]) * (-10000.0f);
    }
  }
}

// ---------------------------------------------------------------------------
// KERPLE bias tables for ALL layers: kbt_all[l][h][d]
// ---------------------------------------------------------------------------
__global__ void kerple_all_kernel(const float* __restrict__ r1,
                                  const float* __restrict__ r2,
                                  const float* __restrict__ r3,
                                  float* __restrict__ kbt_all)
{
  int lh = blockIdx.x;        // l*NH + h, 0..NL*NH
  int d  = threadIdx.x;
  float c1 = fmaxf(r1[lh], 1e-7f);
  float c2 = fmaxf(r2[lh], 1e-7f);
  float c3 = fmaxf(r3[lh], 1e-7f);
  float v = 0.0f;
  if (d > 0) v = -c1 * log1pf(c2 * powf((float)d, c3));
  kbt_all[lh * SQ + d] = v;
}

// ---------------------------------------------------------------------------
// per-layer weight cast fp32 -> bf16, all 4 weight blocks in one launch.
// dst layout: [Wqkv | attn_out_w | glu_w | wo_w]
// ---------------------------------------------------------------------------
#define WS0 (3*HID*HID)     // 1769472
#define WS1 (HID*HID)       //  589824
#define WS2 (2*INTER*HID)   // 4718592
#define WS3 (HID*INTER)     // 2359296
#define WTOT (WS0+WS1+WS2+WS3)  // 9437184

__global__ __launch_bounds__(256) void wcast_layer_kernel(
    const float* __restrict__ w0, const float* __restrict__ w1,
    const float* __restrict__ w2, const float* __restrict__ w3,
    ushort_t* __restrict__ dst)
{
  int i = (blockIdx.x * 256 + threadIdx.x) * 4;
  if (i >= WTOT) return;
  const float* src; int off;
  if (i < WS0)                { src = w0; off = i; }
  else if (i < WS0+WS1)       { src = w1; off = i - WS0; }
  else if (i < WS0+WS1+WS2)   { src = w2; off = i - WS0 - WS1; }
  else                        { src = w3; off = i - WS0 - WS1 - WS2; }
  float4 v = *reinterpret_cast<const float4*>(src + off);
  ushort4 o;
  o.x = f2bf(v.x); o.y = f2bf(v.y); o.z = f2bf(v.z); o.w = f2bf(v.w);
  *reinterpret_cast<ushort4*>(dst + i) = o;
}

// ---------------------------------------------------------------------------
// bf16 MFMA GEMM, 2-phase double-buffered (T3-minimum):
//   per K-step: issue next-tile global_load_lds FIRST, ds_read+MFMA current,
//   one __syncthreads (vmcnt residue drained after compute).
// 128x128 tile, BK=64, 256 threads (4 waves, 2x2 of 64x64), fp32 accum.
// EPI=0: +bias -> fp32 Cf.  EPI=1: plain -> bf16 Cb.  EPI=2: (+bias)*rowscale -> bf16 Cb.
// LDS XOR-swizzled both-sides at 16B-chunk granularity (bank-conflict-free).
// ---------------------------------------------------------------------------
template<int EPI>
__global__ __launch_bounds__(256, 2) void mfma_gemm2(
    const ushort_t* __restrict__ A, const ushort_t* __restrict__ B,
    const float* __restrict__ bias, const float* __restrict__ rowscale,
    float* __restrict__ Cf, ushort_t* __restrict__ Cb, int N, int K)
{
  __shared__ ushort_t As_[2][128 * 64];
  __shared__ ushort_t Bs_[2][128 * 64];
  int tid = threadIdx.x;
  int lane = tid & 63, w = tid >> 6;
  int wr = w >> 1, wc = w & 1;
  int bn = blockIdx.x, bm = blockIdx.y;

  f32x4 acc[4][4];
#pragma unroll
  for (int m = 0; m < 4; ++m)
#pragma unroll
    for (int n = 0; n < 4; ++n) acc[m][n] = (f32x4){0.f, 0.f, 0.f, 0.f};

  // staging geometry: tile = 128 rows x 128 B; wave stages 4 KB = 4 issues.
  int sr[4], sc[4], so[4];
#pragma unroll
  for (int i = 0; i < 4; ++i) {
    int o = w * 4096 + i * 1024 + lane * 16;   // byte offset in tile
    sr[i] = o >> 7;                            // row
    int cl = (o >> 4) & 7;                     // linear 16B chunk in row
    sc[i] = cl ^ (sr[i] & 7);                  // swizzled source chunk
    so[i] = (w * 4096 + i * 1024) >> 1;        // wave-uniform LDS elem base
  }
  const ushort_t* Arow = A + (size_t)bm * 128 * K;
  const ushort_t* Brow = B + (size_t)bn * 128 * K;

  // fragment LDS element offsets (swizzled read)
  int aoff[4][2], boff[4][2];
#pragma unroll
  for (int m = 0; m < 4; ++m)
#pragma unroll
    for (int kh = 0; kh < 2; ++kh) {
      int ra = wr * 64 + m * 16 + (lane & 15);
      int rb = wc * 64 + m * 16 + (lane & 15);
      int ch = (kh * 4 + (lane >> 4)) ^ (lane & 7);
      aoff[m][kh] = ra * 64 + ch * 8;
      boff[m][kh] = rb * 64 + ch * 8;
    }

  int NT = K >> 6;
  // prologue: stage tile 0 into buf 0
#pragma unroll
  for (int i = 0; i < 4; ++i)
    gload_lds16(Arow + (size_t)sr[i] * K + sc[i] * 8, As_[0] + so[i]);
#pragma unroll
  for (int i = 0; i < 4; ++i)
    gload_lds16(Brow + (size_t)sr[i] * K + sc[i] * 8, Bs_[0] + so[i]);
  __syncthreads();

  int cur = 0;
  for (int t = 0; t < NT; ++t) {
    // issue next-tile stage first (in flight under this tile's compute)
    if (t + 1 < NT) {
      int k1 = (t + 1) << 6;
#pragma unroll
      for (int i = 0; i < 4; ++i)
        gload_lds16(Arow + (size_t)sr[i] * K + k1 + sc[i] * 8, As_[cur ^ 1] + so[i]);
#pragma unroll
      for (int i = 0; i < 4; ++i)
        gload_lds16(Brow + (size_t)sr[i] * K + k1 + sc[i] * 8, Bs_[cur ^ 1] + so[i]);
    }
    const ushort_t* Ab = As_[cur];
    const ushort_t* Bb = Bs_[cur];
#pragma unroll
    for (int kh = 0; kh < 2; ++kh) {
      bf16x8 af[4], bf_[4];
#pragma unroll
      for (int m = 0; m < 4; ++m) af[m] = *(const bf16x8*)(Ab + aoff[m][kh]);
#pragma unroll
      for (int n = 0; n < 4; ++n) bf_[n] = *(const bf16x8*)(Bb + boff[n][kh]);
#pragma unroll
      for (int m = 0; m < 4; ++m)
#pragma unroll
        for (int n = 0; n < 4; ++n)
          acc[m][n] = __builtin_amdgcn_mfma_f32_16x16x32_bf16(
              af[m], bf_[n], acc[m][n], 0, 0, 0);
    }
    __syncthreads();   // vmcnt residue + lds reads retired; buffers flip safely
    cur ^= 1;
  }

  // epilogue: C/D layout col=lane&15, row=(lane>>4)*4+j
  int r0 = bm * 128 + wr * 64, c0 = bn * 128 + wc * 64;
#pragma unroll
  for (int m = 0; m < 4; ++m)
#pragma unroll
    for (int n = 0; n < 4; ++n) {
      int col  = c0 + n * 16 + (lane & 15);
      int rowb = r0 + m * 16 + (lane >> 4) * 4;
      if constexpr (EPI == 0) {
        float bv = bias ? bias[col] : 0.0f;
#pragma unroll
        for (int j = 0; j < 4; ++j)
          Cf[(size_t)(rowb + j) * N + col] = acc[m][n][j] + bv;
      } else if constexpr (EPI == 1) {
#pragma unroll
        for (int j = 0; j < 4; ++j)
          Cb[(size_t)(rowb + j) * N + col] = f2bf(acc[m][n][j]);
      } else {
        float bv = bias ? bias[col] : 0.0f;
#pragma unroll
        for (int j = 0; j < 4; ++j) {
          float v = (acc[m][n][j] + bv) * rowscale[rowb + j];
          Cb[(size_t)(rowb + j) * N + col] = f2bf(v);
        }
      }
    }
}

// ---------------------------------------------------------------------------
// GeGLU elementwise: xb = gelu_exact(ga) * gb, bf16 in/out, 8 elems/thread
// ---------------------------------------------------------------------------
__global__ __launch_bounds__(256) void glu_mul_kernel(
    const ushort_t* __restrict__ ga, const ushort_t* __restrict__ gb,
    ushort_t* __restrict__ xb)
{
  int i = (blockIdx.x * 256 + threadIdx.x) * 8;
  u16x8 a = *(const u16x8*)(ga + i);
  u16x8 b = *(const u16x8*)(gb + i);
  u16x8 o;
#pragma unroll
  for (int u = 0; u < 8; ++u) {
    float va = bf2f((ushort_t)a[u]);
    float vb = bf2f((ushort_t)b[u]);
    float ge = 0.5f * va * (1.0f + erff(va * 0.70710678118654752440f));
    o[u] = f2bf(ge * vb);
  }
  *(u16x8*)(xb + i) = o;
}

// ---------------------------------------------------------------------------
// MFMA flash attention (unchanged from round 4; passing, conflict-bounded).
// ---------------------------------------------------------------------------
__global__ __launch_bounds__(256) void attn_mfma(
    const ushort_t* __restrict__ qkvb, const float* __restrict__ kbt,
    const float* __restrict__ maskbias, ushort_t* __restrict__ attnb)
{
  __shared__ ushort_t Ks[64 * 64];   // K[k][d]
  __shared__ ushort_t Vt[64 * 64];   // V^T[d][k]
  __shared__ ushort_t Ps[64 * 64];   // P[q][k]
  __shared__ float    kbs[SQ];
  __shared__ float    mbs[SQ];

  int tid  = threadIdx.x;
  int lane = tid & 63, w = tid >> 6;
  int g = lane >> 4, r = lane & 15;
  int bid = blockIdx.x;
  int qt = bid & 7;
  int hh = (bid >> 3) % NH;
  int b  = bid / (8 * NH);
  int q0 = qt * 64;

  for (int i = tid; i < SQ; i += 256) {
    kbs[i] = kbt[hh * SQ + i];
    mbs[i] = maskbias[b * SQ + i];
  }

  bf16x8 qf[2];
  {
    const ushort_t* qsrc = qkvb + (size_t)(b * SQ + q0 + w * 16 + r) * (3 * HID)
                         + hh * DH + g * 8;
    qf[0] = *(const bf16x8*)(qsrc);
    qf[1] = *(const bf16x8*)(qsrc + 32);
  }

  float m_run[4], l_run[4];
  f32x4 oacc[4];
#pragma unroll
  for (int j = 0; j < 4; ++j) { m_run[j] = -1e30f; l_run[j] = 0.f; }
#pragma unroll
  for (int nd = 0; nd < 4; ++nd) oacc[nd] = (f32x4){0.f, 0.f, 0.f, 0.f};

  int k2 = (tid & 31) * 2, dg = tid >> 5;

  for (int kc = 0; kc < 8; ++kc) {
    __syncthreads();
#pragma unroll
    for (int ii = 0; ii < 2; ++ii) {
      int row = (w * 2 + ii) * 8 + (lane >> 3);
      int c   = lane & 7;
      const ushort_t* src = qkvb + (size_t)(b * SQ + kc * 64 + row) * (3 * HID)
                          + HID + hh * DH + ((c ^ (row & 7)) * 8);
      gload_lds16(src, Ks + (w * 2 + ii) * 512 + lane * 8);
    }
    {
      const ushort_t* v0 = qkvb + (size_t)(b * SQ + kc * 64 + k2) * (3 * HID)
                         + 2 * HID + hh * DH + dg * 8;
      const ushort_t* v1 = v0 + 3 * HID;
      u16x8 a = *(const u16x8*)v0;
      u16x8 c = *(const u16x8*)v1;
#pragma unroll
      for (int u = 0; u < 8; ++u) {
        int d = dg * 8 + u;
        int addr = d * 64 + (((k2 >> 3) ^ (d & 7)) * 8) + (k2 & 7);
        ushort2 pr; pr.x = (ushort_t)a[u]; pr.y = (ushort_t)c[u];
        *(ushort2*)(Vt + addr) = pr;
      }
    }
    __syncthreads();

    f32x4 sacc[4];
#pragma unroll
    for (int n = 0; n < 4; ++n) sacc[n] = (f32x4){0.f, 0.f, 0.f, 0.f};
#pragma unroll
    for (int kh = 0; kh < 2; ++kh) {
#pragma unroll
      for (int n = 0; n < 4; ++n) {
        bf16x8 kf = *(const bf16x8*)(Ks + (n * 16 + r) * 64
                                     + (((g + kh * 4) ^ (r & 7)) * 8));
        sacc[n] = __builtin_amdgcn_mfma_f32_16x16x32_bf16(qf[kh], kf, sacc[n], 0, 0, 0);
      }
    }

    float sval[4][4], mx[4];
#pragma unroll
    for (int j = 0; j < 4; ++j) mx[j] = -1e30f;
#pragma unroll
    for (int n = 0; n < 4; ++n) {
      int kg = kc * 64 + n * 16 + r;
      float mb = mbs[kg];
#pragma unroll
      for (int j = 0; j < 4; ++j) {
        int qg = q0 + w * 16 + g * 4 + j;
        float s = sacc[n][j] * 0.125f + mb + kbs[abs(qg - kg)];
        sval[n][j] = s;
        mx[j] = fmaxf(mx[j], s);
      }
    }
#pragma unroll
    for (int j = 0; j < 4; ++j) {
      mx[j] = fmaxf(mx[j], __shfl_xor(mx[j], 1));
      mx[j] = fmaxf(mx[j], __shfl_xor(mx[j], 2));
      mx[j] = fmaxf(mx[j], __shfl_xor(mx[j], 4));
      mx[j] = fmaxf(mx[j], __shfl_xor(mx[j], 8));
      float mn = fmaxf(m_run[j], mx[j]);
      mx[j] = __expf(m_run[j] - mn);   // reuse as scale
      m_run[j] = mn;
    }
    float rs[4] = {0.f, 0.f, 0.f, 0.f};
#pragma unroll
    for (int n = 0; n < 4; ++n) {
#pragma unroll
      for (int j = 0; j < 4; ++j) {
        float pp = __expf(sval[n][j] - m_run[j]);
        int prow = w * 16 + g * 4 + j;
        int pcol = n * 16 + r;
        Ps[prow * 64 + (((pcol >> 3) ^ (prow & 7)) * 8) + (pcol & 7)] = f2bf(pp);
        rs[j] += pp;
      }
    }
#pragma unroll
    for (int j = 0; j < 4; ++j) {
      rs[j] += __shfl_xor(rs[j], 1);
      rs[j] += __shfl_xor(rs[j], 2);
      rs[j] += __shfl_xor(rs[j], 4);
      rs[j] += __shfl_xor(rs[j], 8);
      l_run[j] = l_run[j] * mx[j] + rs[j];
    }
#pragma unroll
    for (int nd = 0; nd < 4; ++nd)
#pragma unroll
      for (int j = 0; j < 4; ++j) oacc[nd][j] *= mx[j];

#pragma unroll
    for (int kh = 0; kh < 2; ++kh) {
      bf16x8 pa = *(const bf16x8*)(Ps + (w * 16 + r) * 64
                                   + (((g + kh * 4) ^ (r & 7)) * 8));
#pragma unroll
      for (int nd = 0; nd < 4; ++nd) {
        bf16x8 vf = *(const bf16x8*)(Vt + (nd * 16 + r) * 64
                                     + (((g + kh * 4) ^ (r & 7)) * 8));
        oacc[nd] = __builtin_amdgcn_mfma_f32_16x16x32_bf16(pa, vf, oacc[nd], 0, 0, 0);
      }
    }
  }

#pragma unroll
  for (int j = 0; j < 4; ++j) {
    float inv = 1.0f / l_run[j];
    int token = b * SQ + q0 + w * 16 + g * 4 + j;
#pragma unroll
    for (int nd = 0; nd < 4; ++nd)
      attnb[(size_t)token * HID + hh * DH + nd * 16 + r] = f2bf(oacc[nd][j] * inv);
  }
}

// ---------------------------------------------------------------------------
// Residual + LayerNorm + mask: fp32 out + bf16 out
// ---------------------------------------------------------------------------
__global__ __launch_bounds__(256) void ln_res_kernel(
    const float* __restrict__ t, const float* __restrict__ res,
    const float* __restrict__ g, const float* __restrict__ bb,
    const float* __restrict__ maskf, float* __restrict__ out,
    ushort_t* __restrict__ outb)
{
  __shared__ float red[256];
  int row = blockIdx.x, tid = threadIdx.x;
  const float* tp = t   + (size_t)row * HID;
  const float* rp = res + (size_t)row * HID;
  float y0 = tp[tid      ] + rp[tid      ];
  float y1 = tp[tid + 256] + rp[tid + 256];
  float y2 = tp[tid + 512] + rp[tid + 512];

  red[tid] = y0 + y1 + y2; __syncthreads();
  for (int off = 128; off > 0; off >>= 1) {
    if (tid < off) red[tid] += red[tid + off];
    __syncthreads();
  }
  float mu = red[0] * (1.0f / 768.0f); __syncthreads();
  float d0 = y0 - mu, d1 = y1 - mu, d2 = y2 - mu;
  red[tid] = d0*d0 + d1*d1 + d2*d2; __syncthreads();
  for (int off = 128; off > 0; off >>= 1) {
    if (tid < off) red[tid] += red[tid + off];
    __syncthreads();
  }
  float rstd = rsqrtf(red[0] * (1.0f / 768.0f) + 1e-12f);
  float mk = maskf[row];
  float v0 = (d0*rstd*g[tid      ] + bb[tid      ]) * mk;
  float v1 = (d1*rstd*g[tid + 256] + bb[tid + 256]) * mk;
  float v2 = (d2*rstd*g[tid + 512] + bb[tid + 512]) * mk;
  size_t base = (size_t)row * HID;
  out[base + tid      ] = v0;  outb[base + tid      ] = f2bf(v0);
  out[base + tid + 256] = v1;  outb[base + tid + 256] = f2bf(v1);
  out[base + tid + 512] = v2;  outb[base + tid + 512] = f2bf(v2);
}

// ---------------------------------------------------------------------------
__global__ __launch_bounds__(256) void copy_out_kernel(
    const float* __restrict__ h, float* __restrict__ out)
{
  int i = blockIdx.x * 256 + threadIdx.x;
  if (i < M_TOK * HID) out[i] = h[i];
}

// ---------------------------------------------------------------------------
extern "C" void kernel_launch(void* const* d_in, const int* in_sizes, int n_in,
                              void* d_out, int out_size, void* d_ws, size_t ws_size,
                              hipStream_t stream) {
  const float* hidden     = (const float*)d_in[0];
  const float* amask      = (const float*)d_in[1];
  const float* Wqkv_w     = (const float*)d_in[2];
  const float* Wqkv_b     = (const float*)d_in[3];
  const float* attn_out_w = (const float*)d_in[4];
  const float* attn_out_b = (const float*)d_in[5];
  const float* ln1_g      = (const float*)d_in[6];
  const float* ln1_b      = (const float*)d_in[7];
  const float* glu_w      = (const float*)d_in[8];
  const float* wo_w       = (const float*)d_in[9];
  const float* wo_b       = (const float*)d_in[10];
  const float* ln2_g      = (const float*)d_in[11];
  const float* ln2_b      = (const float*)d_in[12];
  const float* r1         = (const float*)d_in[13];
  const float* r2         = (const float*)d_in[14];
  const float* r3         = (const float*)d_in[15];

  // workspace layout (floats)
  float* ws       = (float*)d_ws;
  float* maskf    = ws;                           // 4096
  float* maskbias = maskf    + 4096;              // 4096
  float* kbt_all  = maskbias + 4096;              // NL*NH*SQ = 24576
  float* h        = kbt_all  + NL*NH*SQ;          // 3145728
  float* tbuf     = h    + (size_t)M_TOK*HID;     // 3145728
  float* ao       = tbuf + (size_t)M_TOK*HID;     // 3145728
  // ushorts
  ushort_t* us    = (ushort_t*)(ao + (size_t)M_TOK*HID);
  ushort_t* hb    = us;                           // 3145728
  ushort_t* aob   = hb    + (size_t)M_TOK*HID;    // 3145728
  ushort_t* atnb  = aob   + (size_t)M_TOK*HID;    // 3145728
  ushort_t* qkv_b = atnb  + (size_t)M_TOK*HID;    // 9437184
  ushort_t* xb    = qkv_b + (size_t)M_TOK*3*HID;  // 12582912
  ushort_t* gb    = xb    + (size_t)M_TOK*INTER;  // 12582912
  ushort_t* wbf   = gb    + (size_t)M_TOK*INTER;  // 9437184
  // ga aliases [atnb, qkv_b): 3145728 + 9437184 == 12582912 == M_TOK*INTER.
  // Lifetimes: atnb/qkv_b dead after attn_out GEMM; ga live only GLU->glu_mul.
  ushort_t* ga    = atnb;

  prep_kernel<<<(M_TOK*HID + 255)/256, 256, 0, stream>>>(
      hidden, amask, maskf, maskbias, h, hb);
  kerple_all_kernel<<<NL*NH, SQ, 0, stream>>>(r1, r2, r3, kbt_all);

  for (int l = 0; l < NL; ++l) {
    // ---- cast this layer's weights (one launch) ----
    wcast_layer_kernel<<<(WTOT/4 + 255)/256, 256, 0, stream>>>(
        Wqkv_w     + (size_t)l*WS0,
        attn_out_w + (size_t)l*WS1,
        glu_w      + (size_t)l*WS2,
        wo_w       + (size_t)l*WS3, wbf);
    ushort_t* wqkv = wbf;
    ushort_t* wao  = wbf + WS0;
    ushort_t* wga  = wbf + WS0 + WS1;
    ushort_t* wgb  = wga + (size_t)INTER*HID;
    ushort_t* wwo  = wbf + WS0 + WS1 + WS2;

    // ---- qkv_b = (h @ Wqkv^T + b) * mask  [4096 x 2304] bf16 ----
    mfma_gemm2<2><<<dim3(3*HID/128, M_TOK/128), 256, 0, stream>>>(
        hb, wqkv, Wqkv_b + (size_t)l*3*HID, maskf, nullptr, qkv_b, 3*HID, HID);

    // ---- attention -> atnb (bf16) ----
    attn_mfma<<<BQ*NH*8, 256, 0, stream>>>(
        qkv_b, kbt_all + (size_t)l*NH*SQ, maskbias, atnb);

    // ---- t = attn @ attn_out_w^T + b  [4096 x 768] fp32 ----
    mfma_gemm2<0><<<dim3(HID/128, M_TOK/128), 256, 0, stream>>>(
        atnb, wao, attn_out_b + (size_t)l*HID, nullptr, tbuf, nullptr, HID, HID);

    // ---- ao = LN(t + h) * mask ----
    ln_res_kernel<<<M_TOK, 256, 0, stream>>>(tbuf, h, ln1_g + (size_t)l*HID,
                                             ln1_b + (size_t)l*HID, maskf, ao, aob);

    // ---- GLU halves: ga = ao@Wa^T, gb = ao@Wb^T  [4096 x 3072] bf16 ----
    mfma_gemm2<1><<<dim3(INTER/128, M_TOK/128), 256, 0, stream>>>(
        aob, wga, nullptr, nullptr, nullptr, ga, INTER, HID);
    mfma_gemm2<1><<<dim3(INTER/128, M_TOK/128), 256, 0, stream>>>(
        aob, wgb, nullptr, nullptr, nullptr, gb, INTER, HID);

    // ---- xb = gelu(ga) * gb ----
    glu_mul_kernel<<<(M_TOK*INTER/8 + 255)/256, 256, 0, stream>>>(ga, gb, xb);

    // ---- t = x @ wo^T + wo_b  [4096 x 768] fp32 ----
    mfma_gemm2<0><<<dim3(HID/128, M_TOK/128), 256, 0, stream>>>(
        xb, wwo, wo_b + (size_t)l*HID, nullptr, tbuf, nullptr, HID, INTER);

    // ---- h = LN(t + ao) * mask ----
    ln_res_kernel<<<M_TOK, 256, 0, stream>>>(tbuf, ao, ln2_g + (size_t)l*HID,
                                             ln2_b + (size_t)l*HID, maskf, h, hb);
  }

  copy_out_kernel<<<(M_TOK*HID + 255)/256, 256, 0, stream>>>(h, (float*)d_out);
}

// Round 6
// 834.104 us; speedup vs baseline: 1.2135x; 1.2135x over previous
//
#include <hip/hip_runtime.h>
#include <hip/hip_bf16.h>
#include <math.h>

// Problem dims
#define BQ 8
#define SQ 512
#define HID 768
#define NH 12
#define DH 64
#define INTER 3072
#define NL 4
#define M_TOK (BQ*SQ)   // 4096 tokens

typedef unsigned short ushort_t;
typedef __attribute__((ext_vector_type(8))) short bf16x8;
typedef __attribute__((ext_vector_type(8))) unsigned short u16x8;
typedef __attribute__((ext_vector_type(4))) float f32x4;

__device__ __forceinline__ float bf2f(ushort_t u) {
  union { float f; unsigned int i; } v; v.i = ((unsigned int)u) << 16; return v.f;
}
__device__ __forceinline__ ushort_t f2bf(float f) {
  __hip_bfloat16 h = __float2bfloat16(f);
  return *reinterpret_cast<ushort_t*>(&h);
}

__device__ __forceinline__ void gload_lds16(const ushort_t* g, ushort_t* l) {
  __builtin_amdgcn_global_load_lds(
      (const __attribute__((address_space(1))) void*)g,
      (__attribute__((address_space(3))) void*)l, 16, 0, 0);
}

// ---------------------------------------------------------------------------
// prep: maskf, maskbias, h = hidden*mask (fp32) + hb (bf16)
// ---------------------------------------------------------------------------
__global__ __launch_bounds__(256) void prep_kernel(
    const float* __restrict__ hidden, const float* __restrict__ amask,
    float* __restrict__ maskf, float* __restrict__ maskbias,
    float* __restrict__ h, ushort_t* __restrict__ hb)
{
  int i = blockIdx.x * 256 + threadIdx.x;
  if (i < M_TOK * HID) {
    float m = amask[i / HID];
    float v = hidden[i] * m;
    h[i] = v;
    hb[i] = f2bf(v);
    if (i < M_TOK) {
      maskf[i] = amask[i];
      maskbias[i] = (1.0f - amask[i]) * (-10000.0f);
    }
  }
}

// ---------------------------------------------------------------------------
// KERPLE bias tables for ALL layers: kbt_all[l][h][d]
// ---------------------------------------------------------------------------
__global__ void kerple_all_kernel(const float* __restrict__ r1,
                                  const float* __restrict__ r2,
                                  const float* __restrict__ r3,
                                  float* __restrict__ kbt_all)
{
  int lh = blockIdx.x;        // l*NH + h
  int d  = threadIdx.x;
  float c1 = fmaxf(r1[lh], 1e-7f);
  float c2 = fmaxf(r2[lh], 1e-7f);
  float c3 = fmaxf(r3[lh], 1e-7f);
  float v = 0.0f;
  if (d > 0) v = -c1 * log1pf(c2 * powf((float)d, c3));
  kbt_all[lh * SQ + d] = v;
}

// ---------------------------------------------------------------------------
// per-layer weight cast fp32 -> bf16, all 4 weight blocks in one launch.
// dst layout: [Wqkv | attn_out_w | glu_w | wo_w]
// ---------------------------------------------------------------------------
#define WS0 (3*HID*HID)
#define WS1 (HID*HID)
#define WS2 (2*INTER*HID)
#define WS3 (HID*INTER)
#define WTOT (WS0+WS1+WS2+WS3)

__global__ __launch_bounds__(256) void wcast_layer_kernel(
    const float* __restrict__ w0, const float* __restrict__ w1,
    const float* __restrict__ w2, const float* __restrict__ w3,
    ushort_t* __restrict__ dst)
{
  int i = (blockIdx.x * 256 + threadIdx.x) * 4;
  if (i >= WTOT) return;
  const float* src; int off;
  if (i < WS0)                { src = w0; off = i; }
  else if (i < WS0+WS1)       { src = w1; off = i - WS0; }
  else if (i < WS0+WS1+WS2)   { src = w2; off = i - WS0 - WS1; }
  else                        { src = w3; off = i - WS0 - WS1 - WS2; }
  float4 v = *reinterpret_cast<const float4*>(src + off);
  ushort4 o;
  o.x = f2bf(v.x); o.y = f2bf(v.y); o.z = f2bf(v.z); o.w = f2bf(v.w);
  *reinterpret_cast<ushort4*>(dst + i) = o;
}

// ---------------------------------------------------------------------------
// bf16 MFMA GEMM (single-buffer m97 structure, round-4 proven).
// 128x128 tile, BK=64, 256 threads (4 waves, 2x2 of 64x64), fp32 accum.
// All epilogues write bf16:
//   EPI=0: +bias.  EPI=1: GLU gelu(acc0)*acc1.  EPI=2: (+bias)*rowscale.
// LDS XOR-swizzled both-sides at 16B-chunk granularity (bank-conflict-free).
// ---------------------------------------------------------------------------
template<int NB, int EPI>
__global__ __launch_bounds__(256, 2) void mfma_gemm(
    const ushort_t* __restrict__ A, const ushort_t* __restrict__ B0p,
    const ushort_t* __restrict__ B1p, const float* __restrict__ bias,
    const float* __restrict__ rowscale, ushort_t* __restrict__ Cb,
    int N, int K)
{
  __shared__ ushort_t As_[128 * 64];
  __shared__ ushort_t Bs_[NB][128 * 64];
  int tid = threadIdx.x;
  int lane = tid & 63, w = tid >> 6;
  int wr = w >> 1, wc = w & 1;
  int bn = blockIdx.x, bm = blockIdx.y;

  f32x4 acc[NB][4][4];
#pragma unroll
  for (int p = 0; p < NB; ++p)
#pragma unroll
    for (int m = 0; m < 4; ++m)
#pragma unroll
      for (int n = 0; n < 4; ++n) acc[p][m][n] = (f32x4){0.f, 0.f, 0.f, 0.f};

  int sr[4], sc[4], so[4];
#pragma unroll
  for (int i = 0; i < 4; ++i) {
    int o = w * 4096 + i * 1024 + lane * 16;   // byte offset in tile
    sr[i] = o >> 7;                            // row
    int cl = (o >> 4) & 7;                     // linear 16B chunk in row
    sc[i] = cl ^ (sr[i] & 7);                  // swizzled source chunk
    so[i] = (w * 4096 + i * 1024) >> 1;        // wave-uniform LDS elem base
  }
  const ushort_t* Arow  = A   + (size_t)bm * 128 * K;
  const ushort_t* Brow0 = B0p + (size_t)bn * 128 * K;
  const ushort_t* Brow1 = (NB == 2) ? (B1p + (size_t)bn * 128 * K) : nullptr;

  int aoff[4][2], boff[4][2];
#pragma unroll
  for (int m = 0; m < 4; ++m)
#pragma unroll
    for (int kh = 0; kh < 2; ++kh) {
      int ra = wr * 64 + m * 16 + (lane & 15);
      int rb = wc * 64 + m * 16 + (lane & 15);
      int ch = (kh * 4 + (lane >> 4)) ^ (lane & 7);
      aoff[m][kh] = ra * 64 + ch * 8;
      boff[m][kh] = rb * 64 + ch * 8;
    }

  for (int k0 = 0; k0 < K; k0 += 64) {
#pragma unroll
    for (int i = 0; i < 4; ++i)
      gload_lds16(Arow + (size_t)sr[i] * K + k0 + sc[i] * 8, As_ + so[i]);
#pragma unroll
    for (int i = 0; i < 4; ++i)
      gload_lds16(Brow0 + (size_t)sr[i] * K + k0 + sc[i] * 8, &Bs_[0][so[i]]);
    if constexpr (NB == 2) {
#pragma unroll
      for (int i = 0; i < 4; ++i)
        gload_lds16(Brow1 + (size_t)sr[i] * K + k0 + sc[i] * 8, &Bs_[1][so[i]]);
    }
    __syncthreads();
#pragma unroll
    for (int kh = 0; kh < 2; ++kh) {
      bf16x8 af[4], bf_[4];
#pragma unroll
      for (int m = 0; m < 4; ++m) af[m] = *(const bf16x8*)(As_ + aoff[m][kh]);
#pragma unroll
      for (int n = 0; n < 4; ++n) bf_[n] = *(const bf16x8*)(&Bs_[0][boff[n][kh]]);
#pragma unroll
      for (int m = 0; m < 4; ++m)
#pragma unroll
        for (int n = 0; n < 4; ++n)
          acc[0][m][n] = __builtin_amdgcn_mfma_f32_16x16x32_bf16(
              af[m], bf_[n], acc[0][m][n], 0, 0, 0);
      if constexpr (NB == 2) {
        bf16x8 bg[4];
#pragma unroll
        for (int n = 0; n < 4; ++n) bg[n] = *(const bf16x8*)(&Bs_[1][boff[n][kh]]);
#pragma unroll
        for (int m = 0; m < 4; ++m)
#pragma unroll
          for (int n = 0; n < 4; ++n)
            acc[1][m][n] = __builtin_amdgcn_mfma_f32_16x16x32_bf16(
                af[m], bg[n], acc[1][m][n], 0, 0, 0);
      }
    }
    __syncthreads();
  }

  // epilogue: C/D layout col=lane&15, row=(lane>>4)*4+j
  int r0 = bm * 128 + wr * 64, c0 = bn * 128 + wc * 64;
#pragma unroll
  for (int m = 0; m < 4; ++m)
#pragma unroll
    for (int n = 0; n < 4; ++n) {
      int col  = c0 + n * 16 + (lane & 15);
      int rowb = r0 + m * 16 + (lane >> 4) * 4;
      if constexpr (EPI == 0) {
        float bv = bias ? bias[col] : 0.0f;
#pragma unroll
        for (int j = 0; j < 4; ++j)
          Cb[(size_t)(rowb + j) * N + col] = f2bf(acc[0][m][n][j] + bv);
      } else if constexpr (EPI == 1) {
#pragma unroll
        for (int j = 0; j < 4; ++j) {
          float va = acc[0][m][n][j];
          float vb = acc[1][m][n][j];
          float ge = 0.5f * va * (1.0f + erff(va * 0.70710678118654752440f));
          Cb[(size_t)(rowb + j) * N + col] = f2bf(ge * vb);
        }
      } else {
        float bv = bias ? bias[col] : 0.0f;
#pragma unroll
        for (int j = 0; j < 4; ++j) {
          float v = (acc[0][m][n][j] + bv) * rowscale[rowb + j];
          Cb[(size_t)(rowb + j) * N + col] = f2bf(v);
        }
      }
    }
}

// ---------------------------------------------------------------------------
// MFMA flash attention (round-4 proven) + T5 setprio around MFMA clusters.
// ---------------------------------------------------------------------------
__global__ __launch_bounds__(256) void attn_mfma(
    const ushort_t* __restrict__ qkvb, const float* __restrict__ kbt,
    const float* __restrict__ maskbias, ushort_t* __restrict__ attnb)
{
  __shared__ ushort_t Ks[64 * 64];   // K[k][d]
  __shared__ ushort_t Vt[64 * 64];   // V^T[d][k]
  __shared__ ushort_t Ps[64 * 64];   // P[q][k]
  __shared__ float    kbs[SQ];
  __shared__ float    mbs[SQ];

  int tid  = threadIdx.x;
  int lane = tid & 63, w = tid >> 6;
  int g = lane >> 4, r = lane & 15;
  int bid = blockIdx.x;
  int qt = bid & 7;
  int hh = (bid >> 3) % NH;
  int b  = bid / (8 * NH);
  int q0 = qt * 64;

  for (int i = tid; i < SQ; i += 256) {
    kbs[i] = kbt[hh * SQ + i];
    mbs[i] = maskbias[b * SQ + i];
  }

  bf16x8 qf[2];
  {
    const ushort_t* qsrc = qkvb + (size_t)(b * SQ + q0 + w * 16 + r) * (3 * HID)
                         + hh * DH + g * 8;
    qf[0] = *(const bf16x8*)(qsrc);
    qf[1] = *(const bf16x8*)(qsrc + 32);
  }

  float m_run[4], l_run[4];
  f32x4 oacc[4];
#pragma unroll
  for (int j = 0; j < 4; ++j) { m_run[j] = -1e30f; l_run[j] = 0.f; }
#pragma unroll
  for (int nd = 0; nd < 4; ++nd) oacc[nd] = (f32x4){0.f, 0.f, 0.f, 0.f};

  int k2 = (tid & 31) * 2, dg = tid >> 5;

  for (int kc = 0; kc < 8; ++kc) {
    __syncthreads();
#pragma unroll
    for (int ii = 0; ii < 2; ++ii) {
      int row = (w * 2 + ii) * 8 + (lane >> 3);
      int c   = lane & 7;
      const ushort_t* src = qkvb + (size_t)(b * SQ + kc * 64 + row) * (3 * HID)
                          + HID + hh * DH + ((c ^ (row & 7)) * 8);
      gload_lds16(src, Ks + (w * 2 + ii) * 512 + lane * 8);
    }
    {
      const ushort_t* v0 = qkvb + (size_t)(b * SQ + kc * 64 + k2) * (3 * HID)
                         + 2 * HID + hh * DH + dg * 8;
      const ushort_t* v1 = v0 + 3 * HID;
      u16x8 a = *(const u16x8*)v0;
      u16x8 c = *(const u16x8*)v1;
#pragma unroll
      for (int u = 0; u < 8; ++u) {
        int d = dg * 8 + u;
        int addr = d * 64 + (((k2 >> 3) ^ (d & 7)) * 8) + (k2 & 7);
        ushort2 pr; pr.x = (ushort_t)a[u]; pr.y = (ushort_t)c[u];
        *(ushort2*)(Vt + addr) = pr;
      }
    }
    __syncthreads();

    f32x4 sacc[4];
#pragma unroll
    for (int n = 0; n < 4; ++n) sacc[n] = (f32x4){0.f, 0.f, 0.f, 0.f};
    __builtin_amdgcn_s_setprio(1);
#pragma unroll
    for (int kh = 0; kh < 2; ++kh) {
#pragma unroll
      for (int n = 0; n < 4; ++n) {
        bf16x8 kf = *(const bf16x8*)(Ks + (n * 16 + r) * 64
                                     + (((g + kh * 4) ^ (r & 7)) * 8));
        sacc[n] = __builtin_amdgcn_mfma_f32_16x16x32_bf16(qf[kh], kf, sacc[n], 0, 0, 0);
      }
    }
    __builtin_amdgcn_s_setprio(0);

    float sval[4][4], mx[4];
#pragma unroll
    for (int j = 0; j < 4; ++j) mx[j] = -1e30f;
#pragma unroll
    for (int n = 0; n < 4; ++n) {
      int kg = kc * 64 + n * 16 + r;
      float mb = mbs[kg];
#pragma unroll
      for (int j = 0; j < 4; ++j) {
        int qg = q0 + w * 16 + g * 4 + j;
        float s = sacc[n][j] * 0.125f + mb + kbs[abs(qg - kg)];
        sval[n][j] = s;
        mx[j] = fmaxf(mx[j], s);
      }
    }
#pragma unroll
    for (int j = 0; j < 4; ++j) {
      mx[j] = fmaxf(mx[j], __shfl_xor(mx[j], 1));
      mx[j] = fmaxf(mx[j], __shfl_xor(mx[j], 2));
      mx[j] = fmaxf(mx[j], __shfl_xor(mx[j], 4));
      mx[j] = fmaxf(mx[j], __shfl_xor(mx[j], 8));
      float mn = fmaxf(m_run[j], mx[j]);
      mx[j] = __expf(m_run[j] - mn);   // reuse as scale
      m_run[j] = mn;
    }
    float rs[4] = {0.f, 0.f, 0.f, 0.f};
#pragma unroll
    for (int n = 0; n < 4; ++n) {
#pragma unroll
      for (int j = 0; j < 4; ++j) {
        float pp = __expf(sval[n][j] - m_run[j]);
        int prow = w * 16 + g * 4 + j;
        int pcol = n * 16 + r;
        Ps[prow * 64 + (((pcol >> 3) ^ (prow & 7)) * 8) + (pcol & 7)] = f2bf(pp);
        rs[j] += pp;
      }
    }
#pragma unroll
    for (int j = 0; j < 4; ++j) {
      rs[j] += __shfl_xor(rs[j], 1);
      rs[j] += __shfl_xor(rs[j], 2);
      rs[j] += __shfl_xor(rs[j], 4);
      rs[j] += __shfl_xor(rs[j], 8);
      l_run[j] = l_run[j] * mx[j] + rs[j];
    }
#pragma unroll
    for (int nd = 0; nd < 4; ++nd)
#pragma unroll
      for (int j = 0; j < 4; ++j) oacc[nd][j] *= mx[j];

    __builtin_amdgcn_s_setprio(1);
#pragma unroll
    for (int kh = 0; kh < 2; ++kh) {
      bf16x8 pa = *(const bf16x8*)(Ps + (w * 16 + r) * 64
                                   + (((g + kh * 4) ^ (r & 7)) * 8));
#pragma unroll
      for (int nd = 0; nd < 4; ++nd) {
        bf16x8 vf = *(const bf16x8*)(Vt + (nd * 16 + r) * 64
                                     + (((g + kh * 4) ^ (r & 7)) * 8));
        oacc[nd] = __builtin_amdgcn_mfma_f32_16x16x32_bf16(pa, vf, oacc[nd], 0, 0, 0);
      }
    }
    __builtin_amdgcn_s_setprio(0);
  }

#pragma unroll
  for (int j = 0; j < 4; ++j) {
    float inv = 1.0f / l_run[j];
    int token = b * SQ + q0 + w * 16 + g * 4 + j;
#pragma unroll
    for (int nd = 0; nd < 4; ++nd)
      attnb[(size_t)token * HID + hh * DH + nd * 16 + r] = f2bf(oacc[nd][j] * inv);
  }
}

// ---------------------------------------------------------------------------
// Residual + LayerNorm + mask: wave-shfl reduce (2 barriers).
// t is bf16 (GEMM output), res fp32. out fp32 (residual chain / d_out), outb bf16.
// ---------------------------------------------------------------------------
__global__ __launch_bounds__(256) void ln_res_kernel(
    const ushort_t* __restrict__ t, const float* __restrict__ res,
    const float* __restrict__ g, const float* __restrict__ bb,
    const float* __restrict__ maskf, float* __restrict__ out,
    ushort_t* __restrict__ outb)
{
  __shared__ float part[8];
  int row = blockIdx.x, tid = threadIdx.x;
  int wid = tid >> 6;
  const ushort_t* tp = t + (size_t)row * HID;
  const float*    rp = res + (size_t)row * HID;
  float y0 = bf2f(tp[tid      ]) + rp[tid      ];
  float y1 = bf2f(tp[tid + 256]) + rp[tid + 256];
  float y2 = bf2f(tp[tid + 512]) + rp[tid + 512];

  float s = y0 + y1 + y2;
  s += __shfl_xor(s, 1);  s += __shfl_xor(s, 2);  s += __shfl_xor(s, 4);
  s += __shfl_xor(s, 8);  s += __shfl_xor(s, 16); s += __shfl_xor(s, 32);
  if ((tid & 63) == 0) part[wid] = s;
  __syncthreads();
  float mu = (part[0] + part[1] + part[2] + part[3]) * (1.0f / 768.0f);

  float d0 = y0 - mu, d1 = y1 - mu, d2 = y2 - mu;
  float v = d0*d0 + d1*d1 + d2*d2;
  v += __shfl_xor(v, 1);  v += __shfl_xor(v, 2);  v += __shfl_xor(v, 4);
  v += __shfl_xor(v, 8);  v += __shfl_xor(v, 16); v += __shfl_xor(v, 32);
  if ((tid & 63) == 0) part[4 + wid] = v;
  __syncthreads();
  float rstd = rsqrtf((part[4] + part[5] + part[6] + part[7]) * (1.0f / 768.0f)
                      + 1e-12f);
  float mk = maskf[row];
  float v0 = (d0*rstd*g[tid      ] + bb[tid      ]) * mk;
  float v1 = (d1*rstd*g[tid + 256] + bb[tid + 256]) * mk;
  float v2 = (d2*rstd*g[tid + 512] + bb[tid + 512]) * mk;
  size_t base = (size_t)row * HID;
  out[base + tid      ] = v0;  outb[base + tid      ] = f2bf(v0);
  out[base + tid + 256] = v1;  outb[base + tid + 256] = f2bf(v1);
  out[base + tid + 512] = v2;  outb[base + tid + 512] = f2bf(v2);
}

// ---------------------------------------------------------------------------
extern "C" void kernel_launch(void* const* d_in, const int* in_sizes, int n_in,
                              void* d_out, int out_size, void* d_ws, size_t ws_size,
                              hipStream_t stream) {
  const float* hidden     = (const float*)d_in[0];
  const float* amask      = (const float*)d_in[1];
  const float* Wqkv_w     = (const float*)d_in[2];
  const float* Wqkv_b     = (const float*)d_in[3];
  const float* attn_out_w = (const float*)d_in[4];
  const float* attn_out_b = (const float*)d_in[5];
  const float* ln1_g      = (const float*)d_in[6];
  const float* ln1_b      = (const float*)d_in[7];
  const float* glu_w      = (const float*)d_in[8];
  const float* wo_w       = (const float*)d_in[9];
  const float* wo_b       = (const float*)d_in[10];
  const float* ln2_g      = (const float*)d_in[11];
  const float* ln2_b      = (const float*)d_in[12];
  const float* r1         = (const float*)d_in[13];
  const float* r2         = (const float*)d_in[14];
  const float* r3         = (const float*)d_in[15];

  // workspace layout (floats first)
  float* ws       = (float*)d_ws;
  float* maskf    = ws;                           // 4096
  float* maskbias = maskf    + 4096;              // 4096
  float* kbt_all  = maskbias + 4096;              // NL*NH*SQ = 24576
  float* h        = kbt_all  + NL*NH*SQ;          // 3145728  (fp32 residual)
  float* ao       = h  + (size_t)M_TOK*HID;       // 3145728  (fp32 residual)
  // ushorts
  ushort_t* us    = (ushort_t*)(ao + (size_t)M_TOK*HID);
  ushort_t* hb    = us;                           // 3145728
  ushort_t* aob   = hb    + (size_t)M_TOK*HID;    // 3145728
  ushort_t* atnb  = aob   + (size_t)M_TOK*HID;    // 3145728
  ushort_t* tb    = atnb  + (size_t)M_TOK*HID;    // 3145728 (bf16 GEMM out)
  ushort_t* qkv_b = tb    + (size_t)M_TOK*HID;    // 9437184
  ushort_t* xb    = qkv_b + (size_t)M_TOK*3*HID;  // 12582912
  ushort_t* wbf   = xb    + (size_t)M_TOK*INTER;  // 9437184

  prep_kernel<<<(M_TOK*HID + 255)/256, 256, 0, stream>>>(
      hidden, amask, maskf, maskbias, h, hb);
  kerple_all_kernel<<<NL*NH, SQ, 0, stream>>>(r1, r2, r3, kbt_all);

  for (int l = 0; l < NL; ++l) {
    // ---- cast this layer's weights (one launch) ----
    wcast_layer_kernel<<<(WTOT/4 + 255)/256, 256, 0, stream>>>(
        Wqkv_w     + (size_t)l*WS0,
        attn_out_w + (size_t)l*WS1,
        glu_w      + (size_t)l*WS2,
        wo_w       + (size_t)l*WS3, wbf);
    ushort_t* wqkv = wbf;
    ushort_t* wao  = wbf + WS0;
    ushort_t* wga  = wbf + WS0 + WS1;
    ushort_t* wgb  = wga + (size_t)INTER*HID;
    ushort_t* wwo  = wbf + WS0 + WS1 + WS2;

    // ---- qkv_b = (h @ Wqkv^T + b) * mask  [4096 x 2304] bf16 ----
    mfma_gemm<1,2><<<dim3(3*HID/128, M_TOK/128), 256, 0, stream>>>(
        hb, wqkv, nullptr, Wqkv_b + (size_t)l*3*HID, maskf, qkv_b, 3*HID, HID);

    // ---- attention -> atnb (bf16) ----
    attn_mfma<<<BQ*NH*8, 256, 0, stream>>>(
        qkv_b, kbt_all + (size_t)l*NH*SQ, maskbias, atnb);

    // ---- tb = attn @ attn_out_w^T + b  [4096 x 768] bf16 ----
    mfma_gemm<1,0><<<dim3(HID/128, M_TOK/128), 256, 0, stream>>>(
        atnb, wao, nullptr, attn_out_b + (size_t)l*HID, nullptr, tb, HID, HID);

    // ---- ao = LN(tb + h) * mask  (fp32 + bf16) ----
    ln_res_kernel<<<M_TOK, 256, 0, stream>>>(tb, h, ln1_g + (size_t)l*HID,
                                             ln1_b + (size_t)l*HID, maskf, ao, aob);

    // ---- xb = gelu(ao @ Wa^T) * (ao @ Wb^T)  [4096 x 3072] bf16 ----
    mfma_gemm<2,1><<<dim3(INTER/128, M_TOK/128), 256, 0, stream>>>(
        aob, wga, wgb, nullptr, nullptr, xb, INTER, HID);

    // ---- tb = x @ wo^T + wo_b  [4096 x 768] bf16 ----
    mfma_gemm<1,0><<<dim3(HID/128, M_TOK/128), 256, 0, stream>>>(
        xb, wwo, nullptr, wo_b + (size_t)l*HID, nullptr, tb, HID, INTER);

    // ---- h = LN(tb + ao) * mask ; final layer writes d_out directly ----
    float* hout = (l == NL - 1) ? (float*)d_out : h;
    ln_res_kernel<<<M_TOK, 256, 0, stream>>>(tb, ao, ln2_g + (size_t)l*HID,
                                             ln2_b + (size_t)l*HID, maskf, hout, hb);
  }
}